// Round 4
// baseline (791.605 us; speedup 1.0000x reference)
//
#include <hip/hip_runtime.h>
#include <math.h>

#define NN 50000
#define NE 800000
#define CH 128
#define NG 64
#define BN_EPS 1e-5f
#define POOL_CHUNK 64
#define BKT_SHIFT 9
#define NBKT ((NN + 511) >> 9)              // 98 buckets of 512 nodes
#define PTILE 2048
#define NPART ((NE + PTILE - 1) / PTILE)    // 391 partition blocks
#define CAP 16384                           // per-bucket edge capacity (~8200 real + pad, max ~15880)
#define AGG_NPB 96                          // nodes per agg block
#define AGG_NBLK ((NN + AGG_NPB - 1) / AGG_NPB)   // 521 node-blocks per channel-group

typedef short bfrag8 __attribute__((ext_vector_type(8)));   // 8 bf16 (4 VGPRs)
typedef float facc4 __attribute__((ext_vector_type(4)));    // 4 fp32 acc

__device__ __forceinline__ float gelu_f(float x) {
    return 0.5f * x * (1.0f + erff(x * 0.70710678118654752440f));
}

// bf16 helpers (RNE pack, bit-exact unpack)
__device__ __forceinline__ unsigned int f2bf(float f) {
    unsigned int u = __float_as_uint(f);
    return (u + 0x7FFFu + ((u >> 16) & 1u)) >> 16;
}
__device__ __forceinline__ unsigned int pack_bf2(float lo, float hi) {
    return (f2bf(hi) << 16) | f2bf(lo);
}
__device__ __forceinline__ float bf_lo(unsigned int v) { return __uint_as_float(v << 16); }
__device__ __forceinline__ float bf_hi(unsigned int v) { return __uint_as_float(v & 0xFFFF0000u); }

// ---------------- pass A: partition edges by dst bucket (capacity-strided, 4B packed)
//                   + W-pack blocks appended (blocks >= NPART do wconv work) ----------------
// packed edge: bits [24:16] = dst within bucket (9b), bits [15:0] = src (NN < 65536)
__global__ __launch_bounds__(256) void part_k(const int* __restrict__ ei,
                                              int* __restrict__ btail,
                                              unsigned int* __restrict__ part,
                                              const float* __restrict__ W0,
                                              const float* __restrict__ W1,
                                              const float* __restrict__ W2,
                                              const float* __restrict__ W3,
                                              const float* __restrict__ W4,
                                              unsigned short* __restrict__ wf) {
    int t = threadIdx.x;
    if (blockIdx.x >= NPART) {
        // ---- W -> bf16 B-fragment-order pack ----
        int wb = blockIdx.x - NPART;            // 0..39
        int which = wb >> 3;
        int u = (wb & 7) * 256 + t;             // 0..2047
        const float* W = (which == 0) ? W0 : (which == 1) ? W1 : (which == 2) ? W2
                       : (which == 3) ? W3 : W4;
        unsigned short* dst_wf = wf + (size_t)which * 16384;
        int nt = u >> 8, kc = (u >> 6) & 3, l = u & 63;
        int kbase = kc * 32 + (l >> 4) * 8;
        int n = nt * 16 + (l & 15);
        unsigned int p[4];
        #pragma unroll
        for (int jj = 0; jj < 4; ++jj) {
            float a = W[(kbase + 2 * jj) * 128 + n];
            float b = W[(kbase + 2 * jj + 1) * 128 + n];
            p[jj] = pack_bf2(a, b);
        }
        *(uint4*)(dst_wf + (size_t)u * 8) = make_uint4(p[0], p[1], p[2], p[3]);
        return;
    }

    __shared__ int lh[NBKT];
    __shared__ int gbase[NBKT];
    int base = blockIdx.x * PTILE;
    if (t < NBKT) lh[t] = 0;
    __syncthreads();
    int s[8], d[8], rk[8];
    #pragma unroll
    for (int i = 0; i < 8; ++i) {
        int e = base + i * 256 + t;
        if (e < NE) {
            s[i] = ei[e];
            d[i] = ei[NE + e];
            rk[i] = atomicAdd(&lh[d[i] >> BKT_SHIFT], 1);
        }
    }
    __syncthreads();
    if (t < NBKT && lh[t]) gbase[t] = t * CAP + atomicAdd(&btail[t], lh[t]);
    __syncthreads();
    #pragma unroll
    for (int i = 0; i < 8; ++i) {
        int e = base + i * 256 + t;
        if (e < NE) {
            int b = d[i] >> BKT_SHIFT;
            unsigned int ld = (unsigned int)(d[i] & 511);
            part[gbase[b] + rk[i]] = (ld << 16) | (unsigned int)s[i];
        }
    }
}

// ---------------- pass B: per-bucket count+scan+emit row_ptr/row_cnt/dinv + scatter ----------------
// row_cnt = count PADDED to multiple of 16; pad slots filled with sentinel src NN (zero row).
// csr_src stored as ushort (src < 65536) to halve the per-XCD index stream.
__global__ __launch_bounds__(256) void cscat2_k(const unsigned int* __restrict__ part,
                                                const int* __restrict__ btail,
                                                int* __restrict__ row_ptr,
                                                int* __restrict__ row_cnt,
                                                float* __restrict__ dinv,
                                                unsigned short* __restrict__ csr_src) {
    __shared__ int cnt_l[512];
    __shared__ int off_l[512];
    __shared__ int psc[256];
    int b = blockIdx.x;
    int n0 = b << BKT_SHIFT;
    int t = threadIdx.x;
    cnt_l[t] = 0;
    cnt_l[t + 256] = 0;
    __syncthreads();
    int e0 = b * CAP, e1 = e0 + btail[b];
    for (int e = e0 + t; e < e1; e += 256) {
        int ld = (int)(part[e] >> 16);
        atomicAdd(&cnt_l[ld], 1);
    }
    __syncthreads();
    int c0 = cnt_l[2 * t], c1 = cnt_l[2 * t + 1];
    int p0 = (c0 + 15) & ~15, p1 = (c1 + 15) & ~15;
    psc[t] = p0 + p1;
    __syncthreads();
    for (int off = 1; off < 256; off <<= 1) {
        int a = (t >= off) ? psc[t - off] : 0;
        __syncthreads();
        psc[t] += a;
        __syncthreads();
    }
    int excl = (t == 0) ? 0 : psc[t - 1];
    off_l[2 * t] = excl;
    off_l[2 * t + 1] = excl + p0;
    #pragma unroll
    for (int k = 0; k < 2; ++k) {
        int ln = 2 * t + k;
        int n = n0 + ln;
        if (n < NN) {
            int c = (k == 0) ? c0 : c1;
            int p = (k == 0) ? p0 : p1;
            int o = e0 + off_l[ln];
            row_ptr[n] = o;
            row_cnt[n] = p;
            dinv[n] = rsqrtf((float)c + 1.0f);   // +1 = self loop (real degree)
            for (int z = c; z < p; ++z) csr_src[o + z] = (unsigned short)NN;  // sentinel -> zero row
        }
    }
    __syncthreads();
    cnt_l[t] = 0;
    cnt_l[t + 256] = 0;
    __syncthreads();
    for (int e = e0 + t; e < e1; e += 256) {
        unsigned int p = part[e];
        int s = (int)(p & 0xFFFFu);
        int ld = (int)(p >> 16);
        int pos = e0 + off_l[ld] + atomicAdd(&cnt_l[ld], 1);
        csr_src[pos] = (unsigned short)s;
    }
}

// ---------------- MFMA GEMM body; dinv loads hoisted BEFORE MFMA; epilogue scales row r ----------------
__device__ __forceinline__ void gemm_core(unsigned short* Alds, unsigned short* Wlds,
                                          const unsigned short* wfrag,
                                          const float* __restrict__ dinv, int tid,
                                          int row0, unsigned int* out16) {
    const int w = tid >> 6;
    const int l = tid & 63;
    const int quad = l >> 4;
    const int m = l & 15;

    // hoisted: dinv for the 4 rows this lane owns — issues long before epilogue use
    float dv[4];
    #pragma unroll
    for (int r = 0; r < 4; ++r) {
        int row = row0 + w * 16 + quad * 4 + r;
        dv[r] = (row < NN) ? dinv[row] : 0.f;
    }

    #pragma unroll
    for (int i = 0; i < 8; ++i) {
        int linear = tid + i * 256;
        ((uint4*)Wlds)[linear] = ((const uint4*)wfrag)[linear];
    }
    __syncthreads();

    facc4 acc[8];
    #pragma unroll
    for (int nt = 0; nt < 8; ++nt) acc[nt] = (facc4){0.f, 0.f, 0.f, 0.f};

    #pragma unroll
    for (int kc = 0; kc < 4; ++kc) {
        bfrag8 a = *((const bfrag8*)(Alds + ((size_t)((w * 4 + kc) * 64 + l)) * 8));
        #pragma unroll
        for (int nt = 0; nt < 8; ++nt) {
            bfrag8 b = *((const bfrag8*)(Wlds + ((size_t)((nt * 4 + kc) * 64 + l)) * 8));
            acc[nt] = __builtin_amdgcn_mfma_f32_16x16x32_bf16(a, b, acc[nt], 0, 0, 0);
        }
    }

    // C/D layout: col = nt*16+m, row = w*16 + quad*4 + r;  store dinv[row]*acc
    #pragma unroll
    for (int nt = 0; nt < 8; ++nt) {
        #pragma unroll
        for (int r = 0; r < 4; ++r) {
            int row = row0 + w * 16 + quad * 4 + r;
            if (row < NN)
                ((unsigned short*)out16)[(size_t)row * 128 + nt * 16 + m] =
                    (unsigned short)f2bf(acc[nt][r] * dv[r]);
        }
    }
}

// fp32 input (first conv only, no BN)
__global__ __launch_bounds__(256) void gemm_f32_k(const float* __restrict__ A,
                                                  const unsigned short* __restrict__ wfrag,
                                                  const float* __restrict__ dinv,
                                                  unsigned int* __restrict__ out16) {
    __shared__ unsigned short Alds[8192];
    __shared__ unsigned short Wlds[16384];
    const int tid = threadIdx.x;
    const int row0 = blockIdx.x * 64;
    #pragma unroll
    for (int i = 0; i < 4; ++i) {
        int linear = tid + i * 256;
        int r = linear >> 4;
        int g = linear & 15;
        float4 v0 = make_float4(0.f, 0.f, 0.f, 0.f);
        float4 v1 = make_float4(0.f, 0.f, 0.f, 0.f);
        if (row0 + r < NN) {
            const float4* src = (const float4*)&A[(size_t)(row0 + r) * 128 + g * 8];
            v0 = src[0];
            v1 = src[1];
        }
        int unit = (((r >> 4) * 4 + (g >> 2)) * 64) + ((g & 3) * 16) + (r & 15);
        *(uint4*)(Alds + (size_t)unit * 8) =
            make_uint4(pack_bf2(v0.x, v0.y), pack_bf2(v0.z, v0.w),
                       pack_bf2(v1.x, v1.y), pack_bf2(v1.z, v1.w));
    }
    gemm_core(Alds, Wlds, wfrag, dinv, tid, row0, out16);
}

// bf16 input; if ss != null apply gelu(bn(h)) on load
__global__ __launch_bounds__(256) void gemm_bf16_k(const unsigned int* __restrict__ h16,
                                                   const unsigned short* __restrict__ wfrag,
                                                   const float* __restrict__ ss,
                                                   const float* __restrict__ dinv,
                                                   unsigned int* __restrict__ out16) {
    __shared__ unsigned short Alds[8192];
    __shared__ unsigned short Wlds[16384];
    const int tid = threadIdx.x;
    const int row0 = blockIdx.x * 64;
    #pragma unroll
    for (int i = 0; i < 4; ++i) {
        int linear = tid + i * 256;
        int r = linear >> 4;
        int g = linear & 15;
        uint4 v = make_uint4(0u, 0u, 0u, 0u);
        if (row0 + r < NN)
            v = ((const uint4*)h16)[(size_t)(row0 + r) * 16 + g];
        if (ss) {
            float4 sc0 = ((const float4*)ss)[g * 2];
            float4 sh0 = ((const float4*)ss)[32 + g * 2];
            float4 sc1 = ((const float4*)ss)[g * 2 + 1];
            float4 sh1 = ((const float4*)ss)[32 + g * 2 + 1];
            float f0 = gelu_f(bf_lo(v.x) * sc0.x + sh0.x);
            float f1 = gelu_f(bf_hi(v.x) * sc0.y + sh0.y);
            float f2 = gelu_f(bf_lo(v.y) * sc0.z + sh0.z);
            float f3 = gelu_f(bf_hi(v.y) * sc0.w + sh0.w);
            float f4 = gelu_f(bf_lo(v.z) * sc1.x + sh1.x);
            float f5 = gelu_f(bf_hi(v.z) * sc1.y + sh1.y);
            float f6 = gelu_f(bf_lo(v.w) * sc1.z + sh1.z);
            float f7 = gelu_f(bf_hi(v.w) * sc1.w + sh1.w);
            v = make_uint4(pack_bf2(f0, f1), pack_bf2(f2, f3),
                           pack_bf2(f4, f5), pack_bf2(f6, f7));
        }
        int unit = (((r >> 4) * 4 + (g >> 2)) * 64) + ((g & 3) * 16) + (r & 15);
        *(uint4*)(Alds + (size_t)unit * 8) = v;
    }
    gemm_core(Alds, Wlds, wfrag, dinv, tid, row0, out16);
}

// ---------------- CSR aggregation: channel-sliced for per-XCD L2 residency ----------------
// cg = blockIdx&3 selects a 32-channel (64B, line-aligned) slice; with round-robin block->XCD
// dispatch, slice cg only runs on XCDs {cg, cg+4}, whose gather working set is 50000*64B =
// 3.2MB < 4MiB L2 -> random gathers become L2 hits.
// Wave layout: g = lane>>2 is one of 16 edge slots, q = lane&3 covers the 64B slice as 4 x uint4.
// One gather instruction covers 16 edges. Rows padded to x16 (sentinel zero row NN).
__device__ __forceinline__ void acc8(float* a, uint4 v) {
    a[0] += bf_lo(v.x); a[1] += bf_hi(v.x);
    a[2] += bf_lo(v.y); a[3] += bf_hi(v.y);
    a[4] += bf_lo(v.z); a[5] += bf_hi(v.z);
    a[6] += bf_lo(v.w); a[7] += bf_hi(v.w);
}

__global__ __launch_bounds__(256) void csr_agg_k(const int* __restrict__ row_ptr,
                                                 const int* __restrict__ row_cnt,
                                                 const unsigned short* __restrict__ csr_src,
                                                 const unsigned int* __restrict__ hw16,
                                                 const float* __restrict__ bias,
                                                 const float* __restrict__ dinv,
                                                 unsigned int* __restrict__ out16,
                                                 float* __restrict__ stats) {
    int cg = blockIdx.x & 3;                 // channel group (32 ch, 64B slice)
    int nb = blockIdx.x >> 2;                // node block
    int w = threadIdx.x >> 6;
    int lane = threadIdx.x & 63;
    int g = lane >> 2;                        // edge slot 0..15
    int q = lane & 3;                         // uint4 quarter of the slice

    const unsigned int* __restrict__ hq = hw16 + cg * 16 + q * 4;   // + node*64
    float4 b0 = ((const float4*)bias)[cg * 8 + q * 2];
    float4 b1 = ((const float4*)bias)[cg * 8 + q * 2 + 1];

    float st_s[8] = {0.f, 0.f, 0.f, 0.f, 0.f, 0.f, 0.f, 0.f};
    float st_q[8] = {0.f, 0.f, 0.f, 0.f, 0.f, 0.f, 0.f, 0.f};

    int n0 = nb * AGG_NPB + w * (AGG_NPB / 4);
    int n1 = min(n0 + AGG_NPB / 4, NN);

    int n = n0;
    int jc = 0, cc = 0;
    float dc = 0.f;
    if (n < n1) { jc = row_ptr[n]; cc = row_cnt[n]; dc = dinv[n]; }

    while (n < n1) {
        // prefetch next node's meta — hides under this node's gathers
        int nx = n + 1;
        int jp = 0, cp = 0;
        float dp = 0.f;
        if (nx < n1) { jp = row_ptr[nx]; cp = row_cnt[nx]; dp = dinv[nx]; }

        uint4 sv = *(const uint4*)(hq + (size_t)n * 64);
        float di = dc;
        int j = __builtin_amdgcn_readfirstlane(jc) + g;
        int it = __builtin_amdgcn_readfirstlane(cc) >> 4;   // padded to x16

        float a[8] = {0.f, 0.f, 0.f, 0.f, 0.f, 0.f, 0.f, 0.f};
        for (int t2 = 0; t2 < it; ++t2) {
            int s = csr_src[j];
            uint4 v = *(const uint4*)(hq + (size_t)s * 64);
            acc8(a, v);
            j += 16;
        }

        // reduce across the 16 edge slots (lane bits 2..5)
        #pragma unroll
        for (int d = 0; d < 8; ++d) {
            a[d] += __shfl_xor(a[d], 4, 64);
            a[d] += __shfl_xor(a[d], 8, 64);
            a[d] += __shfl_xor(a[d], 16, 64);
            a[d] += __shfl_xor(a[d], 32, 64);
        }

        float fa[8];
        fa[0] = b0.x + di * (a[0] + bf_lo(sv.x));
        fa[1] = b0.y + di * (a[1] + bf_hi(sv.x));
        fa[2] = b0.z + di * (a[2] + bf_lo(sv.y));
        fa[3] = b0.w + di * (a[3] + bf_hi(sv.y));
        fa[4] = b1.x + di * (a[4] + bf_lo(sv.z));
        fa[5] = b1.y + di * (a[5] + bf_hi(sv.z));
        fa[6] = b1.z + di * (a[6] + bf_lo(sv.w));
        fa[7] = b1.w + di * (a[7] + bf_hi(sv.w));

        if (g == 0) {   // lanes 0..3: coalesced 64B store per node
            uint4 o = make_uint4(pack_bf2(fa[0], fa[1]), pack_bf2(fa[2], fa[3]),
                                 pack_bf2(fa[4], fa[5]), pack_bf2(fa[6], fa[7]));
            *(uint4*)(out16 + (size_t)n * 64 + cg * 16 + q * 4) = o;
            if (stats) {
                #pragma unroll
                for (int d = 0; d < 8; ++d) {
                    st_s[d] += fa[d];
                    st_q[d] += fa[d] * fa[d];
                }
            }
        }

        n = nx;
        jc = jp;
        cc = cp;
        dc = dp;
    }

    if (stats) {
        __shared__ float red[2][4][32];   // [sum|sumsq][wave][slice channel] = 1KB
        if (g == 0) {
            #pragma unroll
            for (int d = 0; d < 8; ++d) {
                red[0][w][q * 8 + d] = st_s[d];
                red[1][w][q * 8 + d] = st_q[d];
            }
        }
        __syncthreads();
        int t = threadIdx.x;
        if (t < 32) {
            float ts = red[0][0][t] + red[0][1][t] + red[0][2][t] + red[0][3][t];
            float tq = red[1][0][t] + red[1][1][t] + red[1][2][t] + red[1][3][t];
            float* dst = stats + (size_t)(blockIdx.x & 63) * 256;
            atomicAdd(&dst[cg * 32 + t], ts);
            atomicAdd(&dst[128 + cg * 32 + t], tq);
        }
    }
}

// ---------------- BN finalize: reduce 64 stat buckets -> scale/shift ----------------
__global__ __launch_bounds__(128) void bn_fin_k(const float* __restrict__ stats,
                                                const float* __restrict__ g,
                                                const float* __restrict__ beta,
                                                float* __restrict__ ss) {
    int c = threadIdx.x;
    float sv = 0.f, qv = 0.f;
    #pragma unroll 8
    for (int i = 0; i < 64; ++i) {
        sv += stats[i * 256 + c];
        qv += stats[i * 256 + 128 + c];
    }
    float mean = sv * (1.0f / NN);
    float var = qv * (1.0f / NN) - mean * mean;
    float sc = g[c] * rsqrtf(var + BN_EPS);
    ss[c] = sc;
    ss[128 + c] = beta[c] - mean * sc;
}

// ---------------- global mean pool sum (bf16 input) ----------------
__global__ __launch_bounds__(128) void pool_sum_k(const unsigned int* __restrict__ h16,
                                                  const int* __restrict__ batch,
                                                  float* __restrict__ sums) {
    int r0 = blockIdx.x * POOL_CHUNK;
    int r1 = min(r0 + POOL_CHUNK, NN);
    if (r0 >= NN) return;
    int c = threadIdx.x;
    int cp = c >> 1, hi = c & 1;
    float acc = 0.f;
    int g = batch[r0];
    for (int r = r0; r < r1; ++r) {
        int gr = batch[r];
        if (gr != g) {
            atomicAdd(&sums[g * 128 + c], acc);
            acc = 0.f;
            g = gr;
        }
        unsigned int v = h16[(size_t)r * 64 + cp];
        acc += hi ? bf_hi(v) : bf_lo(v);
    }
    atomicAdd(&sums[g * 128 + c], acc);
}

__device__ __forceinline__ int lower_bound_dev(const int* __restrict__ a, int n, int key) {
    int lo = 0, hi = n;
    while (lo < hi) {
        int mid = (lo + hi) >> 1;
        if (a[mid] < key) lo = mid + 1; else hi = mid;
    }
    return lo;
}

// ---------------- MLP head (pool-div fused) ----------------
__global__ __launch_bounds__(128) void head_k(const float* __restrict__ psum,
                                              const int* __restrict__ batch,
                                              const float* __restrict__ W0, const float* __restrict__ b0,
                                              const float* __restrict__ W1, const float* __restrict__ b1,
                                              const float* __restrict__ W2, const float* __restrict__ b2,
                                              float* __restrict__ out) {
    __shared__ float r0[128], r1[128];
    int g = blockIdx.x, t = threadIdx.x;
    int a = lower_bound_dev(batch, NN, g);
    int b = lower_bound_dev(batch, NN, g + 1);
    float inv = 1.0f / fmaxf((float)(b - a), 1.0f);
    r0[t] = psum[g * 128 + t] * inv;
    __syncthreads();
    float acc = b0[t];
    for (int k = 0; k < 128; ++k) acc += r0[k] * W0[k * 128 + t];
    r1[t] = gelu_f(acc);
    __syncthreads();
    acc = b1[t];
    for (int k = 0; k < 128; ++k) acc += r1[k] * W1[k * 128 + t];
    float y = gelu_f(acc);
    __syncthreads();
    r0[t] = y;
    __syncthreads();
    if (t < 10) {
        acc = b2[t];
        for (int k = 0; k < 128; ++k) acc += r0[k] * W2[k * 10 + t];
        out[g * 10 + t] = acc;
    }
}

extern "C" void kernel_launch(void* const* d_in, const int* in_sizes, int n_in,
                              void* d_out, int out_size, void* d_ws, size_t ws_size,
                              hipStream_t stream) {
    const float* x      = (const float*)d_in[0];
    const int*   ei     = (const int*)d_in[1];
    const int*   batch  = (const int*)d_in[2];
    const float* Wb0    = (const float*)d_in[4];
    const float* bb0    = (const float*)d_in[5];
    const float* gb0    = (const float*)d_in[6];
    const float* betab0 = (const float*)d_in[7];
    const float* Wb1    = (const float*)d_in[8];
    const float* bb1    = (const float*)d_in[9];
    const float* Wa0    = (const float*)d_in[10];
    const float* ba0    = (const float*)d_in[11];
    const float* ga0    = (const float*)d_in[12];
    const float* bea0   = (const float*)d_in[13];
    const float* Wa1    = (const float*)d_in[14];
    const float* ba1    = (const float*)d_in[15];
    const float* ga1    = (const float*)d_in[16];
    const float* bea1   = (const float*)d_in[17];
    const float* Wa2    = (const float*)d_in[18];
    const float* ba2    = (const float*)d_in[19];
    const float* Wh0    = (const float*)d_in[20];
    const float* bh0    = (const float*)d_in[21];
    const float* Wh1    = (const float*)d_in[22];
    const float* bh1    = (const float*)d_in[23];
    const float* Wh2    = (const float*)d_in[24];
    const float* bh2    = (const float*)d_in[25];
    float* out = (float*)d_out;

    char* ws = (char*)d_ws;
    unsigned int* hw16 = (unsigned int*)ws;             ws += (size_t)(NN + 16) * 64 * 4; // GEMM out + sentinel zero row NN
    unsigned int* hB   = (unsigned int*)ws;             ws += (size_t)NN * 64 * 4;   // conv out (bf16x2)
    unsigned int* hC   = (unsigned int*)ws;             ws += (size_t)NN * 64 * 4;
    float* dinv    = (float*)ws;                        ws += (size_t)NN * 4;
    int*   row_ptr = (int*)ws;                          ws += (size_t)(NN + 4) * 4;
    int*   row_cnt = (int*)ws;                          ws += (size_t)NN * 4;
    unsigned short* csr_src = (unsigned short*)ws;      ws += (size_t)NBKT * CAP * 2;  // strided index space (ushort)
    unsigned int* part = (unsigned int*)ws;             ws += (size_t)NBKT * CAP * 4;  // 4B packed edges
    unsigned short* wf = (unsigned short*)ws;           ws += (size_t)5 * 16384 * 2;
    float* ssbuf   = (float*)ws;                        ws += 256 * 4;
    // ---- zero region (single memset) ----
    char* zbase = ws;
    int*   btail   = (int*)ws;                          ws += 128 * 4;
    float* stats3  = (float*)ws;                        ws += (size_t)3 * 64 * 256 * 4;
    float* psum    = (float*)ws;                        ws += (size_t)NG * CH * 4;
    size_t zbytes = (size_t)(ws - zbase);

    unsigned short* wfb0 = wf;
    unsigned short* wfb1 = wf + 16384;
    unsigned short* wfa0 = wf + 2 * 16384;
    unsigned short* wfa1 = wf + 3 * 16384;
    unsigned short* wfa2 = wf + 4 * 16384;

    float* st0 = stats3;
    float* st1 = stats3 + 64 * 256;
    float* st2 = stats3 + 2 * 64 * 256;

    hipMemsetAsync(zbase, 0, zbytes, stream);
    hipMemsetAsync(hw16 + (size_t)NN * 64, 0, 256, stream);   // sentinel zero row

    // CSR build + W-pack (fused): capacity-strided buckets, 4B packed partition
    part_k<<<NPART + 40, 256, 0, stream>>>(ei, btail, part, Wb0, Wb1, Wa0, Wa1, Wa2, wf);
    cscat2_k<<<NBKT, 256, 0, stream>>>(part, btail, row_ptr, row_cnt, dinv, csr_src);

    auto agg = [&](const float* b, unsigned int* o, float* stats) {
        csr_agg_k<<<AGG_NBLK * 4, 256, 0, stream>>>(row_ptr, row_cnt, csr_src,
                                                    hw16, b, dinv, o, stats);
    };
    auto bn_fin = [&](const float* st, const float* g, const float* beta) {
        bn_fin_k<<<1, 128, 0, stream>>>(st, g, beta, ssbuf);
    };

    // conv b0 (fp32 input x)
    gemm_f32_k<<<(NN + 63) / 64, 256, 0, stream>>>(x, wfb0, dinv, hw16);
    agg(bb0, hB, st0);
    bn_fin(st0, gb0, betab0);
    // conv b1 (BN+GELU fused on load)
    gemm_bf16_k<<<(NN + 63) / 64, 256, 0, stream>>>(hB, wfb1, ssbuf, dinv, hw16);
    agg(bb1, hC, nullptr);
    // conv a0 (no BN on input)
    gemm_bf16_k<<<(NN + 63) / 64, 256, 0, stream>>>(hC, wfa0, nullptr, dinv, hw16);
    agg(ba0, hB, st1);
    bn_fin(st1, ga0, bea0);
    // conv a1
    gemm_bf16_k<<<(NN + 63) / 64, 256, 0, stream>>>(hB, wfa1, ssbuf, dinv, hw16);
    agg(ba1, hC, st2);
    bn_fin(st2, ga1, bea1);
    // conv a2
    gemm_bf16_k<<<(NN + 63) / 64, 256, 0, stream>>>(hC, wfa2, ssbuf, dinv, hw16);
    agg(ba2, hB, nullptr);

    pool_sum_k<<<(NN + POOL_CHUNK - 1) / POOL_CHUNK, 128, 0, stream>>>(hB, batch, psum);
    head_k<<<NG, 128, 0, stream>>>(psum, batch, Wh0, bh0, Wh1, bh1, Wh2, bh2, out);
}

// Round 5
// 479.725 us; speedup vs baseline: 1.6501x; 1.6501x over previous
//
#include <hip/hip_runtime.h>
#include <math.h>

#define NN 50000
#define NE 800000
#define CH 128
#define NG 64
#define BN_EPS 1e-5f
#define POOL_CHUNK 64
#define BKT_SHIFT 9
#define NBKT ((NN + 511) >> 9)              // 98 buckets of 512 nodes
#define PTILE 2048
#define NPART ((NE + PTILE - 1) / PTILE)    // 391 partition blocks
#define CAP 16384                           // per-bucket edge capacity (~8200 real + <=512*15 pad = 15880 max)

typedef short bfrag8 __attribute__((ext_vector_type(8)));   // 8 bf16 (4 VGPRs)
typedef float facc4 __attribute__((ext_vector_type(4)));    // 4 fp32 acc

__device__ __forceinline__ float gelu_f(float x) {
    return 0.5f * x * (1.0f + erff(x * 0.70710678118654752440f));
}

// bf16 helpers (RNE pack, bit-exact unpack)
__device__ __forceinline__ unsigned int f2bf(float f) {
    unsigned int u = __float_as_uint(f);
    return (u + 0x7FFFu + ((u >> 16) & 1u)) >> 16;
}
__device__ __forceinline__ unsigned int pack_bf2(float lo, float hi) {
    return (f2bf(hi) << 16) | f2bf(lo);
}
__device__ __forceinline__ float bf_lo(unsigned int v) { return __uint_as_float(v << 16); }
__device__ __forceinline__ float bf_hi(unsigned int v) { return __uint_as_float(v & 0xFFFF0000u); }

// ---------------- pass A: partition edges by dst bucket (capacity-strided, 4B packed)
//                   + W-pack blocks appended (blocks >= NPART do wconv work) ----------------
// packed edge: bits [24:16] = dst within bucket (9b), bits [15:0] = src (NN < 65536)
__global__ __launch_bounds__(256) void part_k(const int* __restrict__ ei,
                                              int* __restrict__ btail,
                                              unsigned int* __restrict__ part,
                                              const float* __restrict__ W0,
                                              const float* __restrict__ W1,
                                              const float* __restrict__ W2,
                                              const float* __restrict__ W3,
                                              const float* __restrict__ W4,
                                              unsigned short* __restrict__ wf) {
    int t = threadIdx.x;
    if (blockIdx.x >= NPART) {
        // ---- W -> bf16 B-fragment-order pack ----
        int wb = blockIdx.x - NPART;            // 0..39
        int which = wb >> 3;
        int u = (wb & 7) * 256 + t;             // 0..2047
        const float* W = (which == 0) ? W0 : (which == 1) ? W1 : (which == 2) ? W2
                       : (which == 3) ? W3 : W4;
        unsigned short* dst_wf = wf + (size_t)which * 16384;
        int nt = u >> 8, kc = (u >> 6) & 3, l = u & 63;
        int kbase = kc * 32 + (l >> 4) * 8;
        int n = nt * 16 + (l & 15);
        unsigned int p[4];
        #pragma unroll
        for (int jj = 0; jj < 4; ++jj) {
            float a = W[(kbase + 2 * jj) * 128 + n];
            float b = W[(kbase + 2 * jj + 1) * 128 + n];
            p[jj] = pack_bf2(a, b);
        }
        *(uint4*)(dst_wf + (size_t)u * 8) = make_uint4(p[0], p[1], p[2], p[3]);
        return;
    }

    __shared__ int lh[NBKT];
    __shared__ int gbase[NBKT];
    int base = blockIdx.x * PTILE;
    if (t < NBKT) lh[t] = 0;
    __syncthreads();
    int s[8], d[8], rk[8];
    #pragma unroll
    for (int i = 0; i < 8; ++i) {
        int e = base + i * 256 + t;
        if (e < NE) {
            s[i] = ei[e];
            d[i] = ei[NE + e];
            rk[i] = atomicAdd(&lh[d[i] >> BKT_SHIFT], 1);
        }
    }
    __syncthreads();
    if (t < NBKT && lh[t]) gbase[t] = t * CAP + atomicAdd(&btail[t], lh[t]);
    __syncthreads();
    #pragma unroll
    for (int i = 0; i < 8; ++i) {
        int e = base + i * 256 + t;
        if (e < NE) {
            int b = d[i] >> BKT_SHIFT;
            unsigned int ld = (unsigned int)(d[i] & 511);
            part[gbase[b] + rk[i]] = (ld << 16) | (unsigned int)s[i];
        }
    }
}

// ---------------- pass B: per-bucket count+scan+emit row_ptr/row_cnt/dinv + scatter ----------------
// row_cnt = count PADDED to multiple of 16; pad slots filled with sentinel src NN (zero row).
__global__ __launch_bounds__(256) void cscat2_k(const unsigned int* __restrict__ part,
                                                const int* __restrict__ btail,
                                                int* __restrict__ row_ptr,
                                                int* __restrict__ row_cnt,
                                                float* __restrict__ dinv,
                                                int* __restrict__ csr_src) {
    __shared__ int cnt_l[512];
    __shared__ int off_l[512];
    __shared__ int psc[256];
    int b = blockIdx.x;
    int n0 = b << BKT_SHIFT;
    int t = threadIdx.x;
    cnt_l[t] = 0;
    cnt_l[t + 256] = 0;
    __syncthreads();
    int e0 = b * CAP, e1 = e0 + btail[b];
    for (int e = e0 + t; e < e1; e += 256) {
        int ld = (int)(part[e] >> 16);
        atomicAdd(&cnt_l[ld], 1);
    }
    __syncthreads();
    int c0 = cnt_l[2 * t], c1 = cnt_l[2 * t + 1];
    int p0 = (c0 + 15) & ~15, p1 = (c1 + 15) & ~15;
    psc[t] = p0 + p1;
    __syncthreads();
    for (int off = 1; off < 256; off <<= 1) {
        int a = (t >= off) ? psc[t - off] : 0;
        __syncthreads();
        psc[t] += a;
        __syncthreads();
    }
    int excl = (t == 0) ? 0 : psc[t - 1];
    off_l[2 * t] = excl;
    off_l[2 * t + 1] = excl + p0;
    #pragma unroll
    for (int k = 0; k < 2; ++k) {
        int ln = 2 * t + k;
        int n = n0 + ln;
        if (n < NN) {
            int c = (k == 0) ? c0 : c1;
            int p = (k == 0) ? p0 : p1;
            int o = e0 + off_l[ln];
            row_ptr[n] = o;
            row_cnt[n] = p;
            dinv[n] = rsqrtf((float)c + 1.0f);   // +1 = self loop (real degree)
            for (int z = c; z < p; ++z) csr_src[o + z] = NN;   // sentinel -> zero row
        }
    }
    __syncthreads();
    cnt_l[t] = 0;
    cnt_l[t + 256] = 0;
    __syncthreads();
    for (int e = e0 + t; e < e1; e += 256) {
        unsigned int p = part[e];
        int s = (int)(p & 0xFFFFu);
        int ld = (int)(p >> 16);
        int pos = e0 + off_l[ld] + atomicAdd(&cnt_l[ld], 1);
        csr_src[pos] = s;
    }
}

// ---------------- MFMA GEMM compute body (Alds/Wlds must be staged + synced by caller);
//                  dinv loads hoisted BEFORE MFMA; epilogue scales row r ----------------
__device__ __forceinline__ void gemm_compute(const unsigned short* Alds,
                                             const unsigned short* Wlds,
                                             const float* __restrict__ dinv, int tid,
                                             int row0, unsigned int* out16) {
    const int w = tid >> 6;
    const int l = tid & 63;
    const int quad = l >> 4;
    const int m = l & 15;

    // hoisted: dinv for the 4 rows this lane owns — issues long before epilogue use
    float dv[4];
    #pragma unroll
    for (int r = 0; r < 4; ++r) {
        int row = row0 + w * 16 + quad * 4 + r;
        dv[r] = (row < NN) ? dinv[row] : 0.f;
    }

    facc4 acc[8];
    #pragma unroll
    for (int nt = 0; nt < 8; ++nt) acc[nt] = (facc4){0.f, 0.f, 0.f, 0.f};

    #pragma unroll
    for (int kc = 0; kc < 4; ++kc) {
        bfrag8 a = *((const bfrag8*)(Alds + ((size_t)((w * 4 + kc) * 64 + l)) * 8));
        #pragma unroll
        for (int nt = 0; nt < 8; ++nt) {
            bfrag8 b = *((const bfrag8*)(Wlds + ((size_t)((nt * 4 + kc) * 64 + l)) * 8));
            acc[nt] = __builtin_amdgcn_mfma_f32_16x16x32_bf16(a, b, acc[nt], 0, 0, 0);
        }
    }

    // C/D layout: col = nt*16+m, row = w*16 + quad*4 + r;  store dinv[row]*acc
    #pragma unroll
    for (int nt = 0; nt < 8; ++nt) {
        #pragma unroll
        for (int r = 0; r < 4; ++r) {
            int row = row0 + w * 16 + quad * 4 + r;
            if (row < NN)
                ((unsigned short*)out16)[(size_t)row * 128 + nt * 16 + m] =
                    (unsigned short)f2bf(acc[nt][r] * dv[r]);
        }
    }
}

// fp32 input (first conv only, no BN). 128 rows/block = 2 chunks; W staged ONCE per block.
__global__ __launch_bounds__(256) void gemm_f32_k(const float* __restrict__ A,
                                                  const unsigned short* __restrict__ wfrag,
                                                  const float* __restrict__ dinv,
                                                  unsigned int* __restrict__ out16) {
    __shared__ unsigned short Alds[8192];
    __shared__ unsigned short Wlds[16384];
    const int tid = threadIdx.x;
    #pragma unroll
    for (int i = 0; i < 8; ++i) {
        int linear = tid + i * 256;
        ((uint4*)Wlds)[linear] = ((const uint4*)wfrag)[linear];
    }
    #pragma unroll
    for (int chunk = 0; chunk < 2; ++chunk) {
        const int row0 = blockIdx.x * 128 + chunk * 64;
        if (chunk) __syncthreads();   // all waves done reading Alds of prev chunk
        #pragma unroll
        for (int i = 0; i < 4; ++i) {
            int linear = tid + i * 256;
            int r = linear >> 4;
            int g = linear & 15;
            float4 v0 = make_float4(0.f, 0.f, 0.f, 0.f);
            float4 v1 = make_float4(0.f, 0.f, 0.f, 0.f);
            if (row0 + r < NN) {
                const float4* src = (const float4*)&A[(size_t)(row0 + r) * 128 + g * 8];
                v0 = src[0];
                v1 = src[1];
            }
            int unit = (((r >> 4) * 4 + (g >> 2)) * 64) + ((g & 3) * 16) + (r & 15);
            *(uint4*)(Alds + (size_t)unit * 8) =
                make_uint4(pack_bf2(v0.x, v0.y), pack_bf2(v0.z, v0.w),
                           pack_bf2(v1.x, v1.y), pack_bf2(v1.z, v1.w));
        }
        __syncthreads();
        gemm_compute(Alds, Wlds, dinv, tid, row0, out16);
    }
}

// bf16 input; if ss != null apply gelu(bn(h)) on load. 128 rows/block, W staged once.
__global__ __launch_bounds__(256) void gemm_bf16_k(const unsigned int* __restrict__ h16,
                                                   const unsigned short* __restrict__ wfrag,
                                                   const float* __restrict__ ss,
                                                   const float* __restrict__ dinv,
                                                   unsigned int* __restrict__ out16) {
    __shared__ unsigned short Alds[8192];
    __shared__ unsigned short Wlds[16384];
    const int tid = threadIdx.x;
    #pragma unroll
    for (int i = 0; i < 8; ++i) {
        int linear = tid + i * 256;
        ((uint4*)Wlds)[linear] = ((const uint4*)wfrag)[linear];
    }
    #pragma unroll
    for (int chunk = 0; chunk < 2; ++chunk) {
        const int row0 = blockIdx.x * 128 + chunk * 64;
        if (chunk) __syncthreads();   // all waves done reading Alds of prev chunk
        #pragma unroll
        for (int i = 0; i < 4; ++i) {
            int linear = tid + i * 256;
            int r = linear >> 4;
            int g = linear & 15;
            uint4 v = make_uint4(0u, 0u, 0u, 0u);
            if (row0 + r < NN)
                v = ((const uint4*)h16)[(size_t)(row0 + r) * 16 + g];
            if (ss) {
                float4 sc0 = ((const float4*)ss)[g * 2];
                float4 sh0 = ((const float4*)ss)[32 + g * 2];
                float4 sc1 = ((const float4*)ss)[g * 2 + 1];
                float4 sh1 = ((const float4*)ss)[32 + g * 2 + 1];
                float f0 = gelu_f(bf_lo(v.x) * sc0.x + sh0.x);
                float f1 = gelu_f(bf_hi(v.x) * sc0.y + sh0.y);
                float f2 = gelu_f(bf_lo(v.y) * sc0.z + sh0.z);
                float f3 = gelu_f(bf_hi(v.y) * sc0.w + sh0.w);
                float f4 = gelu_f(bf_lo(v.z) * sc1.x + sh1.x);
                float f5 = gelu_f(bf_hi(v.z) * sc1.y + sh1.y);
                float f6 = gelu_f(bf_lo(v.w) * sc1.z + sh1.z);
                float f7 = gelu_f(bf_hi(v.w) * sc1.w + sh1.w);
                v = make_uint4(pack_bf2(f0, f1), pack_bf2(f2, f3),
                               pack_bf2(f4, f5), pack_bf2(f6, f7));
            }
            int unit = (((r >> 4) * 4 + (g >> 2)) * 64) + ((g & 3) * 16) + (r & 15);
            *(uint4*)(Alds + (size_t)unit * 8) = v;
        }
        __syncthreads();
        gemm_compute(Alds, Wlds, dinv, tid, row0, out16);
    }
}

// ---------------- CSR aggregation: TWO consecutive nodes per wave, interleaved chains ----------------
// Lane layout: q = lane&15 covers the 256B row as 16 x uint4; g = lane>>4 is the edge slot.
// Rows padded to x16 edges (sentinel zero row NN) -> every node is N iterations of
// {int4 idx load; 4 uint4 gathers}, no tails. Both nodes' loads are issued together in the
// common (1-iter each) case, doubling memory-level parallelism per wave.
__device__ __forceinline__ void acc8(float* a, uint4 v) {
    a[0] += bf_lo(v.x); a[1] += bf_hi(v.x);
    a[2] += bf_lo(v.y); a[3] += bf_hi(v.y);
    a[4] += bf_lo(v.z); a[5] += bf_hi(v.z);
    a[6] += bf_lo(v.w); a[7] += bf_hi(v.w);
}

__global__ __launch_bounds__(256) void csr_agg_k(const int* __restrict__ row_ptr,
                                                 const int* __restrict__ row_cnt,
                                                 const int* __restrict__ csr_src,
                                                 const unsigned int* __restrict__ hw16,
                                                 const float* __restrict__ bias,
                                                 const float* __restrict__ dinv,
                                                 unsigned int* __restrict__ out16,
                                                 float* __restrict__ stats) {
    int wave = (blockIdx.x * 256 + threadIdx.x) >> 6;   // 0..24999, exactly NN/2
    int lane = threadIdx.x & 63;
    int q = lane & 15;
    int g = lane >> 4;
    int n0 = wave * 2;
    int n1 = n0 + 1;

    const unsigned int* __restrict__ hq = hw16 + (size_t)q * 4;

    // issue all independent loads for BOTH nodes up front
    int j0 = row_ptr[n0], c0 = row_cnt[n0];
    int j1 = row_ptr[n1], c1 = row_cnt[n1];
    float di0 = dinv[n0];
    float di1 = dinv[n1];
    uint4 sv0 = *(const uint4*)(hq + (size_t)n0 * 64);
    uint4 sv1 = *(const uint4*)(hq + (size_t)n1 * 64);
    float4 b0 = ((const float4*)bias)[q * 2];
    float4 b1 = ((const float4*)bias)[q * 2 + 1];

    j0 = __builtin_amdgcn_readfirstlane(j0);
    j1 = __builtin_amdgcn_readfirstlane(j1);
    int it0 = __builtin_amdgcn_readfirstlane(c0) >> 4;   // padded to x16
    int it1 = __builtin_amdgcn_readfirstlane(c1) >> 4;

    float a0[8] = {0.f, 0.f, 0.f, 0.f, 0.f, 0.f, 0.f, 0.f};
    float a1[8] = {0.f, 0.f, 0.f, 0.f, 0.f, 0.f, 0.f, 0.f};

    // interleaved: both nodes' idx loads issue first, then all 8 gathers
    while (it0 > 0 && it1 > 0) {
        int4 s0 = *(const int4*)(csr_src + j0 + 4 * g);
        int4 s1 = *(const int4*)(csr_src + j1 + 4 * g);
        j0 += 16; j1 += 16; --it0; --it1;
        uint4 w0 = *(const uint4*)(hq + (size_t)s0.x * 64);
        uint4 w1 = *(const uint4*)(hq + (size_t)s0.y * 64);
        uint4 w2 = *(const uint4*)(hq + (size_t)s0.z * 64);
        uint4 w3 = *(const uint4*)(hq + (size_t)s0.w * 64);
        uint4 x0 = *(const uint4*)(hq + (size_t)s1.x * 64);
        uint4 x1 = *(const uint4*)(hq + (size_t)s1.y * 64);
        uint4 x2 = *(const uint4*)(hq + (size_t)s1.z * 64);
        uint4 x3 = *(const uint4*)(hq + (size_t)s1.w * 64);
        acc8(a0, w0); acc8(a0, w1); acc8(a0, w2); acc8(a0, w3);
        acc8(a1, x0); acc8(a1, x1); acc8(a1, x2); acc8(a1, x3);
    }
    while (it0 > 0) {
        int4 s0 = *(const int4*)(csr_src + j0 + 4 * g);
        j0 += 16; --it0;
        uint4 w0 = *(const uint4*)(hq + (size_t)s0.x * 64);
        uint4 w1 = *(const uint4*)(hq + (size_t)s0.y * 64);
        uint4 w2 = *(const uint4*)(hq + (size_t)s0.z * 64);
        uint4 w3 = *(const uint4*)(hq + (size_t)s0.w * 64);
        acc8(a0, w0); acc8(a0, w1); acc8(a0, w2); acc8(a0, w3);
    }
    while (it1 > 0) {
        int4 s1 = *(const int4*)(csr_src + j1 + 4 * g);
        j1 += 16; --it1;
        uint4 x0 = *(const uint4*)(hq + (size_t)s1.x * 64);
        uint4 x1 = *(const uint4*)(hq + (size_t)s1.y * 64);
        uint4 x2 = *(const uint4*)(hq + (size_t)s1.z * 64);
        uint4 x3 = *(const uint4*)(hq + (size_t)s1.w * 64);
        acc8(a1, x0); acc8(a1, x1); acc8(a1, x2); acc8(a1, x3);
    }

    // sum the 4 edge-groups: lanes {l, l^16, l^32, l^48} hold the same channels
    #pragma unroll
    for (int d = 0; d < 8; ++d) {
        a0[d] += __shfl_xor(a0[d], 16, 64);
        a0[d] += __shfl_xor(a0[d], 32, 64);
        a1[d] += __shfl_xor(a1[d], 16, 64);
        a1[d] += __shfl_xor(a1[d], 32, 64);
    }

    float fa0[8], fa1[8];
    fa0[0] = b0.x + di0 * (a0[0] + bf_lo(sv0.x));
    fa0[1] = b0.y + di0 * (a0[1] + bf_hi(sv0.x));
    fa0[2] = b0.z + di0 * (a0[2] + bf_lo(sv0.y));
    fa0[3] = b0.w + di0 * (a0[3] + bf_hi(sv0.y));
    fa0[4] = b1.x + di0 * (a0[4] + bf_lo(sv0.z));
    fa0[5] = b1.y + di0 * (a0[5] + bf_hi(sv0.z));
    fa0[6] = b1.z + di0 * (a0[6] + bf_lo(sv0.w));
    fa0[7] = b1.w + di0 * (a0[7] + bf_hi(sv0.w));
    fa1[0] = b0.x + di1 * (a1[0] + bf_lo(sv1.x));
    fa1[1] = b0.y + di1 * (a1[1] + bf_hi(sv1.x));
    fa1[2] = b0.z + di1 * (a1[2] + bf_lo(sv1.y));
    fa1[3] = b0.w + di1 * (a1[3] + bf_hi(sv1.y));
    fa1[4] = b1.x + di1 * (a1[4] + bf_lo(sv1.z));
    fa1[5] = b1.y + di1 * (a1[5] + bf_hi(sv1.z));
    fa1[6] = b1.z + di1 * (a1[6] + bf_lo(sv1.w));
    fa1[7] = b1.w + di1 * (a1[7] + bf_hi(sv1.w));

    if (lane < 16) {
        uint4 o0 = make_uint4(pack_bf2(fa0[0], fa0[1]), pack_bf2(fa0[2], fa0[3]),
                              pack_bf2(fa0[4], fa0[5]), pack_bf2(fa0[6], fa0[7]));
        uint4 o1 = make_uint4(pack_bf2(fa1[0], fa1[1]), pack_bf2(fa1[2], fa1[3]),
                              pack_bf2(fa1[4], fa1[5]), pack_bf2(fa1[6], fa1[7]));
        *(uint4*)(out16 + (size_t)n0 * 64 + q * 4) = o0;
        *(uint4*)(out16 + (size_t)n1 * 64 + q * 4) = o1;
    }

    if (stats) {
        __shared__ float red[2][4][128];   // [sum|sumsq][wave][channel] = 4KB
        int w = threadIdx.x >> 6;
        if (lane < 16) {
            #pragma unroll
            for (int d = 0; d < 8; ++d) {
                red[0][w][q * 8 + d] = fa0[d] + fa1[d];
                red[1][w][q * 8 + d] = fa0[d] * fa0[d] + fa1[d] * fa1[d];
            }
        }
        __syncthreads();
        int t = threadIdx.x;
        if (t < 128) {
            float ts = red[0][0][t] + red[0][1][t] + red[0][2][t] + red[0][3][t];
            float tq = red[1][0][t] + red[1][1][t] + red[1][2][t] + red[1][3][t];
            float* dst = stats + (size_t)(blockIdx.x & 63) * 256;
            atomicAdd(&dst[t], ts);
            atomicAdd(&dst[128 + t], tq);
        }
    }
}

// ---------------- BN finalize: reduce 64 stat buckets -> scale/shift ----------------
__global__ __launch_bounds__(128) void bn_fin_k(const float* __restrict__ stats,
                                                const float* __restrict__ g,
                                                const float* __restrict__ beta,
                                                float* __restrict__ ss) {
    int c = threadIdx.x;
    float sv = 0.f, qv = 0.f;
    #pragma unroll 8
    for (int i = 0; i < 64; ++i) {
        sv += stats[i * 256 + c];
        qv += stats[i * 256 + 128 + c];
    }
    float mean = sv * (1.0f / NN);
    float var = qv * (1.0f / NN) - mean * mean;
    float sc = g[c] * rsqrtf(var + BN_EPS);
    ss[c] = sc;
    ss[128 + c] = beta[c] - mean * sc;
}

// ---------------- global mean pool sum (bf16 input) ----------------
__global__ __launch_bounds__(128) void pool_sum_k(const unsigned int* __restrict__ h16,
                                                  const int* __restrict__ batch,
                                                  float* __restrict__ sums) {
    int r0 = blockIdx.x * POOL_CHUNK;
    int r1 = min(r0 + POOL_CHUNK, NN);
    if (r0 >= NN) return;
    int c = threadIdx.x;
    int cp = c >> 1, hi = c & 1;
    float acc = 0.f;
    int g = batch[r0];
    for (int r = r0; r < r1; ++r) {
        int gr = batch[r];
        if (gr != g) {
            atomicAdd(&sums[g * 128 + c], acc);
            acc = 0.f;
            g = gr;
        }
        unsigned int v = h16[(size_t)r * 64 + cp];
        acc += hi ? bf_hi(v) : bf_lo(v);
    }
    atomicAdd(&sums[g * 128 + c], acc);
}

__device__ __forceinline__ int lower_bound_dev(const int* __restrict__ a, int n, int key) {
    int lo = 0, hi = n;
    while (lo < hi) {
        int mid = (lo + hi) >> 1;
        if (a[mid] < key) lo = mid + 1; else hi = mid;
    }
    return lo;
}

// ---------------- MLP head (pool-div fused) ----------------
__global__ __launch_bounds__(128) void head_k(const float* __restrict__ psum,
                                              const int* __restrict__ batch,
                                              const float* __restrict__ W0, const float* __restrict__ b0,
                                              const float* __restrict__ W1, const float* __restrict__ b1,
                                              const float* __restrict__ W2, const float* __restrict__ b2,
                                              float* __restrict__ out) {
    __shared__ float r0[128], r1[128];
    int g = blockIdx.x, t = threadIdx.x;
    int a = lower_bound_dev(batch, NN, g);
    int b = lower_bound_dev(batch, NN, g + 1);
    float inv = 1.0f / fmaxf((float)(b - a), 1.0f);
    r0[t] = psum[g * 128 + t] * inv;
    __syncthreads();
    float acc = b0[t];
    for (int k = 0; k < 128; ++k) acc += r0[k] * W0[k * 128 + t];
    r1[t] = gelu_f(acc);
    __syncthreads();
    acc = b1[t];
    for (int k = 0; k < 128; ++k) acc += r1[k] * W1[k * 128 + t];
    float y = gelu_f(acc);
    __syncthreads();
    r0[t] = y;
    __syncthreads();
    if (t < 10) {
        acc = b2[t];
        for (int k = 0; k < 128; ++k) acc += r0[k] * W2[k * 10 + t];
        out[g * 10 + t] = acc;
    }
}

extern "C" void kernel_launch(void* const* d_in, const int* in_sizes, int n_in,
                              void* d_out, int out_size, void* d_ws, size_t ws_size,
                              hipStream_t stream) {
    const float* x      = (const float*)d_in[0];
    const int*   ei     = (const int*)d_in[1];
    const int*   batch  = (const int*)d_in[2];
    const float* Wb0    = (const float*)d_in[4];
    const float* bb0    = (const float*)d_in[5];
    const float* gb0    = (const float*)d_in[6];
    const float* betab0 = (const float*)d_in[7];
    const float* Wb1    = (const float*)d_in[8];
    const float* bb1    = (const float*)d_in[9];
    const float* Wa0    = (const float*)d_in[10];
    const float* ba0    = (const float*)d_in[11];
    const float* ga0    = (const float*)d_in[12];
    const float* bea0   = (const float*)d_in[13];
    const float* Wa1    = (const float*)d_in[14];
    const float* ba1    = (const float*)d_in[15];
    const float* ga1    = (const float*)d_in[16];
    const float* bea1   = (const float*)d_in[17];
    const float* Wa2    = (const float*)d_in[18];
    const float* ba2    = (const float*)d_in[19];
    const float* Wh0    = (const float*)d_in[20];
    const float* bh0    = (const float*)d_in[21];
    const float* Wh1    = (const float*)d_in[22];
    const float* bh1    = (const float*)d_in[23];
    const float* Wh2    = (const float*)d_in[24];
    const float* bh2    = (const float*)d_in[25];
    float* out = (float*)d_out;

    char* ws = (char*)d_ws;
    unsigned int* hw16 = (unsigned int*)ws;             ws += (size_t)(NN + 16) * 64 * 4; // GEMM out + sentinel zero row NN
    unsigned int* hB   = (unsigned int*)ws;             ws += (size_t)NN * 64 * 4;   // conv out (bf16x2)
    unsigned int* hC   = (unsigned int*)ws;             ws += (size_t)NN * 64 * 4;
    float* dinv    = (float*)ws;                        ws += (size_t)NN * 4;
    int*   row_ptr = (int*)ws;                          ws += (size_t)(NN + 4) * 4;
    int*   row_cnt = (int*)ws;                          ws += (size_t)NN * 4;
    int*   csr_src = (int*)ws;                          ws += (size_t)NBKT * CAP * 4;  // strided index space
    unsigned int* part = (unsigned int*)ws;             ws += (size_t)NBKT * CAP * 4;  // 4B packed edges
    unsigned short* wf = (unsigned short*)ws;           ws += (size_t)5 * 16384 * 2;
    float* ssbuf   = (float*)ws;                        ws += 256 * 4;
    // ---- zero region (single memset) ----
    char* zbase = ws;
    int*   btail   = (int*)ws;                          ws += 128 * 4;
    float* stats3  = (float*)ws;                        ws += (size_t)3 * 64 * 256 * 4;
    float* psum    = (float*)ws;                        ws += (size_t)NG * CH * 4;
    size_t zbytes = (size_t)(ws - zbase);

    unsigned short* wfb0 = wf;
    unsigned short* wfb1 = wf + 16384;
    unsigned short* wfa0 = wf + 2 * 16384;
    unsigned short* wfa1 = wf + 3 * 16384;
    unsigned short* wfa2 = wf + 4 * 16384;

    float* st0 = stats3;
    float* st1 = stats3 + 64 * 256;
    float* st2 = stats3 + 2 * 64 * 256;

    hipMemsetAsync(zbase, 0, zbytes, stream);
    hipMemsetAsync(hw16 + (size_t)NN * 64, 0, 256, stream);   // sentinel zero row

    // CSR build + W-pack (fused): capacity-strided buckets, 4B packed partition
    part_k<<<NPART + 40, 256, 0, stream>>>(ei, btail, part, Wb0, Wb1, Wa0, Wa1, Wa2, wf);
    cscat2_k<<<NBKT, 256, 0, stream>>>(part, btail, row_ptr, row_cnt, dinv, csr_src);

    auto agg = [&](const float* b, unsigned int* o, float* stats) {
        csr_agg_k<<<(NN / 2 * 64) / 256, 256, 0, stream>>>(row_ptr, row_cnt, csr_src,
                                                           hw16, b, dinv, o, stats);
    };
    auto bn_fin = [&](const float* st, const float* g, const float* beta) {
        bn_fin_k<<<1, 128, 0, stream>>>(st, g, beta, ssbuf);
    };

    // conv b0 (fp32 input x)
    gemm_f32_k<<<(NN + 127) / 128, 256, 0, stream>>>(x, wfb0, dinv, hw16);
    agg(bb0, hB, st0);
    bn_fin(st0, gb0, betab0);
    // conv b1 (BN+GELU fused on load)
    gemm_bf16_k<<<(NN + 127) / 128, 256, 0, stream>>>(hB, wfb1, ssbuf, dinv, hw16);
    agg(bb1, hC, nullptr);
    // conv a0 (no BN on input)
    gemm_bf16_k<<<(NN + 127) / 128, 256, 0, stream>>>(hC, wfa0, nullptr, dinv, hw16);
    agg(ba0, hB, st1);
    bn_fin(st1, ga0, bea0);
    // conv a1
    gemm_bf16_k<<<(NN + 127) / 128, 256, 0, stream>>>(hB, wfa1, ssbuf, dinv, hw16);
    agg(ba1, hC, st2);
    bn_fin(st2, ga1, bea1);
    // conv a2
    gemm_bf16_k<<<(NN + 127) / 128, 256, 0, stream>>>(hC, wfa2, ssbuf, dinv, hw16);
    agg(ba2, hB, nullptr);

    pool_sum_k<<<(NN + POOL_CHUNK - 1) / POOL_CHUNK, 128, 0, stream>>>(hB, batch, psum);
    head_k<<<NG, 128, 0, stream>>>(psum, batch, Wh0, bh0, Wh1, bh1, Wh2, bh2, out);
}

// Round 6
// 455.650 us; speedup vs baseline: 1.7373x; 1.0528x over previous
//
#include <hip/hip_runtime.h>
#include <math.h>

#define NN 50000
#define NE 800000
#define CH 128
#define NG 64
#define BN_EPS 1e-5f
#define POOL_CHUNK 64
#define BKT_SHIFT 9
#define NBKT ((NN + 511) >> 9)              // 98 buckets of 512 nodes
#define PTILE 2048
#define NPART ((NE + PTILE - 1) / PTILE)    // 391 partition blocks
#define CAP 16384                           // per-bucket edge capacity (~8200 real + <=512*15 pad = 15880 max)

typedef short bfrag8 __attribute__((ext_vector_type(8)));   // 8 bf16 (4 VGPRs)
typedef float facc4 __attribute__((ext_vector_type(4)));    // 4 fp32 acc

__device__ __forceinline__ float gelu_f(float x) {
    return 0.5f * x * (1.0f + erff(x * 0.70710678118654752440f));
}

// bf16 helpers (RNE pack, bit-exact unpack)
__device__ __forceinline__ unsigned int f2bf(float f) {
    unsigned int u = __float_as_uint(f);
    return (u + 0x7FFFu + ((u >> 16) & 1u)) >> 16;
}
__device__ __forceinline__ unsigned int pack_bf2(float lo, float hi) {
    return (f2bf(hi) << 16) | f2bf(lo);
}
__device__ __forceinline__ float bf_lo(unsigned int v) { return __uint_as_float(v << 16); }
__device__ __forceinline__ float bf_hi(unsigned int v) { return __uint_as_float(v & 0xFFFF0000u); }

// ---------------- pass A: partition edges by dst bucket (capacity-strided, 4B packed)
//                   + W-pack blocks appended (blocks >= NPART do wconv work) ----------------
// packed edge: bits [24:16] = dst within bucket (9b), bits [15:0] = src (NN < 65536)
__global__ __launch_bounds__(256) void part_k(const int* __restrict__ ei,
                                              int* __restrict__ btail,
                                              unsigned int* __restrict__ part,
                                              const float* __restrict__ W0,
                                              const float* __restrict__ W1,
                                              const float* __restrict__ W2,
                                              const float* __restrict__ W3,
                                              const float* __restrict__ W4,
                                              unsigned short* __restrict__ wf) {
    int t = threadIdx.x;
    if (blockIdx.x >= NPART) {
        // ---- W -> bf16 B-fragment-order pack ----
        int wb = blockIdx.x - NPART;            // 0..39
        int which = wb >> 3;
        int u = (wb & 7) * 256 + t;             // 0..2047
        const float* W = (which == 0) ? W0 : (which == 1) ? W1 : (which == 2) ? W2
                       : (which == 3) ? W3 : W4;
        unsigned short* dst_wf = wf + (size_t)which * 16384;
        int nt = u >> 8, kc = (u >> 6) & 3, l = u & 63;
        int kbase = kc * 32 + (l >> 4) * 8;
        int n = nt * 16 + (l & 15);
        unsigned int p[4];
        #pragma unroll
        for (int jj = 0; jj < 4; ++jj) {
            float a = W[(kbase + 2 * jj) * 128 + n];
            float b = W[(kbase + 2 * jj + 1) * 128 + n];
            p[jj] = pack_bf2(a, b);
        }
        *(uint4*)(dst_wf + (size_t)u * 8) = make_uint4(p[0], p[1], p[2], p[3]);
        return;
    }

    __shared__ int lh[NBKT];
    __shared__ int gbase[NBKT];
    int base = blockIdx.x * PTILE;
    if (t < NBKT) lh[t] = 0;
    __syncthreads();
    int s[8], d[8], rk[8];
    #pragma unroll
    for (int i = 0; i < 8; ++i) {
        int e = base + i * 256 + t;
        if (e < NE) {
            s[i] = ei[e];
            d[i] = ei[NE + e];
            rk[i] = atomicAdd(&lh[d[i] >> BKT_SHIFT], 1);
        }
    }
    __syncthreads();
    if (t < NBKT && lh[t]) gbase[t] = t * CAP + atomicAdd(&btail[t], lh[t]);
    __syncthreads();
    #pragma unroll
    for (int i = 0; i < 8; ++i) {
        int e = base + i * 256 + t;
        if (e < NE) {
            int b = d[i] >> BKT_SHIFT;
            unsigned int ld = (unsigned int)(d[i] & 511);
            part[gbase[b] + rk[i]] = (ld << 16) | (unsigned int)s[i];
        }
    }
}

// ---------------- pass B: per-bucket count+scan+emit row_ptr/row_cnt/dinv + scatter ----------------
// row_cnt = count PADDED to multiple of 16; pad slots filled with sentinel src NN (zero row).
__global__ __launch_bounds__(256) void cscat2_k(const unsigned int* __restrict__ part,
                                                const int* __restrict__ btail,
                                                int* __restrict__ row_ptr,
                                                int* __restrict__ row_cnt,
                                                float* __restrict__ dinv,
                                                int* __restrict__ csr_src) {
    __shared__ int cnt_l[512];
    __shared__ int off_l[512];
    __shared__ int psc[256];
    int b = blockIdx.x;
    int n0 = b << BKT_SHIFT;
    int t = threadIdx.x;
    cnt_l[t] = 0;
    cnt_l[t + 256] = 0;
    __syncthreads();
    int e0 = b * CAP, e1 = e0 + btail[b];
    for (int e = e0 + t; e < e1; e += 256) {
        int ld = (int)(part[e] >> 16);
        atomicAdd(&cnt_l[ld], 1);
    }
    __syncthreads();
    int c0 = cnt_l[2 * t], c1 = cnt_l[2 * t + 1];
    int p0 = (c0 + 15) & ~15, p1 = (c1 + 15) & ~15;
    psc[t] = p0 + p1;
    __syncthreads();
    for (int off = 1; off < 256; off <<= 1) {
        int a = (t >= off) ? psc[t - off] : 0;
        __syncthreads();
        psc[t] += a;
        __syncthreads();
    }
    int excl = (t == 0) ? 0 : psc[t - 1];
    off_l[2 * t] = excl;
    off_l[2 * t + 1] = excl + p0;
    #pragma unroll
    for (int k = 0; k < 2; ++k) {
        int ln = 2 * t + k;
        int n = n0 + ln;
        if (n < NN) {
            int c = (k == 0) ? c0 : c1;
            int p = (k == 0) ? p0 : p1;
            int o = e0 + off_l[ln];
            row_ptr[n] = o;
            row_cnt[n] = p;
            dinv[n] = rsqrtf((float)c + 1.0f);   // +1 = self loop (real degree)
            for (int z = c; z < p; ++z) csr_src[o + z] = NN;   // sentinel -> zero row
        }
    }
    __syncthreads();
    cnt_l[t] = 0;
    cnt_l[t + 256] = 0;
    __syncthreads();
    for (int e = e0 + t; e < e1; e += 256) {
        unsigned int p = part[e];
        int s = (int)(p & 0xFFFFu);
        int ld = (int)(p >> 16);
        int pos = e0 + off_l[ld] + atomicAdd(&cnt_l[ld], 1);
        csr_src[pos] = s;
    }
}

// ---------------- MFMA GEMM body; dinv loads hoisted BEFORE MFMA; epilogue scales row r ----------------
__device__ __forceinline__ void gemm_core(unsigned short* Alds, unsigned short* Wlds,
                                          const unsigned short* wfrag,
                                          const float* __restrict__ dinv, int tid,
                                          int row0, unsigned int* out16) {
    const int w = tid >> 6;
    const int l = tid & 63;
    const int quad = l >> 4;
    const int m = l & 15;

    // hoisted: dinv for the 4 rows this lane owns — issues long before epilogue use
    float dv[4];
    #pragma unroll
    for (int r = 0; r < 4; ++r) {
        int row = row0 + w * 16 + quad * 4 + r;
        dv[r] = (row < NN) ? dinv[row] : 0.f;
    }

    #pragma unroll
    for (int i = 0; i < 8; ++i) {
        int linear = tid + i * 256;
        ((uint4*)Wlds)[linear] = ((const uint4*)wfrag)[linear];
    }
    __syncthreads();

    facc4 acc[8];
    #pragma unroll
    for (int nt = 0; nt < 8; ++nt) acc[nt] = (facc4){0.f, 0.f, 0.f, 0.f};

    #pragma unroll
    for (int kc = 0; kc < 4; ++kc) {
        bfrag8 a = *((const bfrag8*)(Alds + ((size_t)((w * 4 + kc) * 64 + l)) * 8));
        #pragma unroll
        for (int nt = 0; nt < 8; ++nt) {
            bfrag8 b = *((const bfrag8*)(Wlds + ((size_t)((nt * 4 + kc) * 64 + l)) * 8));
            acc[nt] = __builtin_amdgcn_mfma_f32_16x16x32_bf16(a, b, acc[nt], 0, 0, 0);
        }
    }

    // C/D layout: col = nt*16+m, row = w*16 + quad*4 + r;  store dinv[row]*acc
    #pragma unroll
    for (int nt = 0; nt < 8; ++nt) {
        #pragma unroll
        for (int r = 0; r < 4; ++r) {
            int row = row0 + w * 16 + quad * 4 + r;
            if (row < NN)
                ((unsigned short*)out16)[(size_t)row * 128 + nt * 16 + m] =
                    (unsigned short)f2bf(acc[nt][r] * dv[r]);
        }
    }
}

// fp32 input (first conv only, no BN)
__global__ __launch_bounds__(256) void gemm_f32_k(const float* __restrict__ A,
                                                  const unsigned short* __restrict__ wfrag,
                                                  const float* __restrict__ dinv,
                                                  unsigned int* __restrict__ out16) {
    __shared__ unsigned short Alds[8192];
    __shared__ unsigned short Wlds[16384];
    const int tid = threadIdx.x;
    const int row0 = blockIdx.x * 64;
    #pragma unroll
    for (int i = 0; i < 4; ++i) {
        int linear = tid + i * 256;
        int r = linear >> 4;
        int g = linear & 15;
        float4 v0 = make_float4(0.f, 0.f, 0.f, 0.f);
        float4 v1 = make_float4(0.f, 0.f, 0.f, 0.f);
        if (row0 + r < NN) {
            const float4* src = (const float4*)&A[(size_t)(row0 + r) * 128 + g * 8];
            v0 = src[0];
            v1 = src[1];
        }
        int unit = (((r >> 4) * 4 + (g >> 2)) * 64) + ((g & 3) * 16) + (r & 15);
        *(uint4*)(Alds + (size_t)unit * 8) =
            make_uint4(pack_bf2(v0.x, v0.y), pack_bf2(v0.z, v0.w),
                       pack_bf2(v1.x, v1.y), pack_bf2(v1.z, v1.w));
    }
    gemm_core(Alds, Wlds, wfrag, dinv, tid, row0, out16);
}

// bf16 input; if ss != null apply gelu(bn(h)) on load
__global__ __launch_bounds__(256) void gemm_bf16_k(const unsigned int* __restrict__ h16,
                                                   const unsigned short* __restrict__ wfrag,
                                                   const float* __restrict__ ss,
                                                   const float* __restrict__ dinv,
                                                   unsigned int* __restrict__ out16) {
    __shared__ unsigned short Alds[8192];
    __shared__ unsigned short Wlds[16384];
    const int tid = threadIdx.x;
    const int row0 = blockIdx.x * 64;
    #pragma unroll
    for (int i = 0; i < 4; ++i) {
        int linear = tid + i * 256;
        int r = linear >> 4;
        int g = linear & 15;
        uint4 v = make_uint4(0u, 0u, 0u, 0u);
        if (row0 + r < NN)
            v = ((const uint4*)h16)[(size_t)(row0 + r) * 16 + g];
        if (ss) {
            float4 sc0 = ((const float4*)ss)[g * 2];
            float4 sh0 = ((const float4*)ss)[32 + g * 2];
            float4 sc1 = ((const float4*)ss)[g * 2 + 1];
            float4 sh1 = ((const float4*)ss)[32 + g * 2 + 1];
            float f0 = gelu_f(bf_lo(v.x) * sc0.x + sh0.x);
            float f1 = gelu_f(bf_hi(v.x) * sc0.y + sh0.y);
            float f2 = gelu_f(bf_lo(v.y) * sc0.z + sh0.z);
            float f3 = gelu_f(bf_hi(v.y) * sc0.w + sh0.w);
            float f4 = gelu_f(bf_lo(v.z) * sc1.x + sh1.x);
            float f5 = gelu_f(bf_hi(v.z) * sc1.y + sh1.y);
            float f6 = gelu_f(bf_lo(v.w) * sc1.z + sh1.z);
            float f7 = gelu_f(bf_hi(v.w) * sc1.w + sh1.w);
            v = make_uint4(pack_bf2(f0, f1), pack_bf2(f2, f3),
                           pack_bf2(f4, f5), pack_bf2(f6, f7));
        }
        int unit = (((r >> 4) * 4 + (g >> 2)) * 64) + ((g & 3) * 16) + (r & 15);
        *(uint4*)(Alds + (size_t)unit * 8) = v;
    }
    gemm_core(Alds, Wlds, wfrag, dinv, tid, row0, out16);
}

// ---------------- CSR aggregation: TWO consecutive nodes per wave, interleaved chains ----------------
// Lane layout: q = lane&15 covers the 256B row as 16 x uint4; g = lane>>4 is the edge slot.
// Rows padded to x16 edges (sentinel zero row NN) -> every node is N iterations of
// {int4 idx load; 4 uint4 gathers}, no tails. Both nodes' loads are issued together in the
// common (1-iter each) case, doubling memory-level parallelism per wave.
__device__ __forceinline__ void acc8(float* a, uint4 v) {
    a[0] += bf_lo(v.x); a[1] += bf_hi(v.x);
    a[2] += bf_lo(v.y); a[3] += bf_hi(v.y);
    a[4] += bf_lo(v.z); a[5] += bf_hi(v.z);
    a[6] += bf_lo(v.w); a[7] += bf_hi(v.w);
}

__global__ __launch_bounds__(256) void csr_agg_k(const int* __restrict__ row_ptr,
                                                 const int* __restrict__ row_cnt,
                                                 const int* __restrict__ csr_src,
                                                 const unsigned int* __restrict__ hw16,
                                                 const float* __restrict__ bias,
                                                 const float* __restrict__ dinv,
                                                 unsigned int* __restrict__ out16,
                                                 float* __restrict__ stats) {
    int wave = (blockIdx.x * 256 + threadIdx.x) >> 6;   // 0..24999, exactly NN/2
    int lane = threadIdx.x & 63;
    int q = lane & 15;
    int g = lane >> 4;
    int n0 = wave * 2;
    int n1 = n0 + 1;

    const unsigned int* __restrict__ hq = hw16 + (size_t)q * 4;

    // issue all independent loads for BOTH nodes up front
    int j0 = row_ptr[n0], c0 = row_cnt[n0];
    int j1 = row_ptr[n1], c1 = row_cnt[n1];
    float di0 = dinv[n0];
    float di1 = dinv[n1];
    uint4 sv0 = *(const uint4*)(hq + (size_t)n0 * 64);
    uint4 sv1 = *(const uint4*)(hq + (size_t)n1 * 64);
    float4 b0 = ((const float4*)bias)[q * 2];
    float4 b1 = ((const float4*)bias)[q * 2 + 1];

    j0 = __builtin_amdgcn_readfirstlane(j0);
    j1 = __builtin_amdgcn_readfirstlane(j1);
    int it0 = __builtin_amdgcn_readfirstlane(c0) >> 4;   // padded to x16
    int it1 = __builtin_amdgcn_readfirstlane(c1) >> 4;

    float a0[8] = {0.f, 0.f, 0.f, 0.f, 0.f, 0.f, 0.f, 0.f};
    float a1[8] = {0.f, 0.f, 0.f, 0.f, 0.f, 0.f, 0.f, 0.f};

    // interleaved: both nodes' idx loads issue first, then all 8 gathers
    while (it0 > 0 && it1 > 0) {
        int4 s0 = *(const int4*)(csr_src + j0 + 4 * g);
        int4 s1 = *(const int4*)(csr_src + j1 + 4 * g);
        j0 += 16; j1 += 16; --it0; --it1;
        uint4 w0 = *(const uint4*)(hq + (size_t)s0.x * 64);
        uint4 w1 = *(const uint4*)(hq + (size_t)s0.y * 64);
        uint4 w2 = *(const uint4*)(hq + (size_t)s0.z * 64);
        uint4 w3 = *(const uint4*)(hq + (size_t)s0.w * 64);
        uint4 x0 = *(const uint4*)(hq + (size_t)s1.x * 64);
        uint4 x1 = *(const uint4*)(hq + (size_t)s1.y * 64);
        uint4 x2 = *(const uint4*)(hq + (size_t)s1.z * 64);
        uint4 x3 = *(const uint4*)(hq + (size_t)s1.w * 64);
        acc8(a0, w0); acc8(a0, w1); acc8(a0, w2); acc8(a0, w3);
        acc8(a1, x0); acc8(a1, x1); acc8(a1, x2); acc8(a1, x3);
    }
    while (it0 > 0) {
        int4 s0 = *(const int4*)(csr_src + j0 + 4 * g);
        j0 += 16; --it0;
        uint4 w0 = *(const uint4*)(hq + (size_t)s0.x * 64);
        uint4 w1 = *(const uint4*)(hq + (size_t)s0.y * 64);
        uint4 w2 = *(const uint4*)(hq + (size_t)s0.z * 64);
        uint4 w3 = *(const uint4*)(hq + (size_t)s0.w * 64);
        acc8(a0, w0); acc8(a0, w1); acc8(a0, w2); acc8(a0, w3);
    }
    while (it1 > 0) {
        int4 s1 = *(const int4*)(csr_src + j1 + 4 * g);
        j1 += 16; --it1;
        uint4 x0 = *(const uint4*)(hq + (size_t)s1.x * 64);
        uint4 x1 = *(const uint4*)(hq + (size_t)s1.y * 64);
        uint4 x2 = *(const uint4*)(hq + (size_t)s1.z * 64);
        uint4 x3 = *(const uint4*)(hq + (size_t)s1.w * 64);
        acc8(a1, x0); acc8(a1, x1); acc8(a1, x2); acc8(a1, x3);
    }

    // sum the 4 edge-groups: lanes {l, l^16, l^32, l^48} hold the same channels
    #pragma unroll
    for (int d = 0; d < 8; ++d) {
        a0[d] += __shfl_xor(a0[d], 16, 64);
        a0[d] += __shfl_xor(a0[d], 32, 64);
        a1[d] += __shfl_xor(a1[d], 16, 64);
        a1[d] += __shfl_xor(a1[d], 32, 64);
    }

    float fa0[8], fa1[8];
    fa0[0] = b0.x + di0 * (a0[0] + bf_lo(sv0.x));
    fa0[1] = b0.y + di0 * (a0[1] + bf_hi(sv0.x));
    fa0[2] = b0.z + di0 * (a0[2] + bf_lo(sv0.y));
    fa0[3] = b0.w + di0 * (a0[3] + bf_hi(sv0.y));
    fa0[4] = b1.x + di0 * (a0[4] + bf_lo(sv0.z));
    fa0[5] = b1.y + di0 * (a0[5] + bf_hi(sv0.z));
    fa0[6] = b1.z + di0 * (a0[6] + bf_lo(sv0.w));
    fa0[7] = b1.w + di0 * (a0[7] + bf_hi(sv0.w));
    fa1[0] = b0.x + di1 * (a1[0] + bf_lo(sv1.x));
    fa1[1] = b0.y + di1 * (a1[1] + bf_hi(sv1.x));
    fa1[2] = b0.z + di1 * (a1[2] + bf_lo(sv1.y));
    fa1[3] = b0.w + di1 * (a1[3] + bf_hi(sv1.y));
    fa1[4] = b1.x + di1 * (a1[4] + bf_lo(sv1.z));
    fa1[5] = b1.y + di1 * (a1[5] + bf_hi(sv1.z));
    fa1[6] = b1.z + di1 * (a1[6] + bf_lo(sv1.w));
    fa1[7] = b1.w + di1 * (a1[7] + bf_hi(sv1.w));

    if (lane < 16) {
        uint4 o0 = make_uint4(pack_bf2(fa0[0], fa0[1]), pack_bf2(fa0[2], fa0[3]),
                              pack_bf2(fa0[4], fa0[5]), pack_bf2(fa0[6], fa0[7]));
        uint4 o1 = make_uint4(pack_bf2(fa1[0], fa1[1]), pack_bf2(fa1[2], fa1[3]),
                              pack_bf2(fa1[4], fa1[5]), pack_bf2(fa1[6], fa1[7]));
        *(uint4*)(out16 + (size_t)n0 * 64 + q * 4) = o0;
        *(uint4*)(out16 + (size_t)n1 * 64 + q * 4) = o1;
    }

    if (stats) {
        __shared__ float red[2][4][128];   // [sum|sumsq][wave][channel] = 4KB
        int w = threadIdx.x >> 6;
        if (lane < 16) {
            #pragma unroll
            for (int d = 0; d < 8; ++d) {
                red[0][w][q * 8 + d] = fa0[d] + fa1[d];
                red[1][w][q * 8 + d] = fa0[d] * fa0[d] + fa1[d] * fa1[d];
            }
        }
        __syncthreads();
        int t = threadIdx.x;
        if (t < 128) {
            float ts = red[0][0][t] + red[0][1][t] + red[0][2][t] + red[0][3][t];
            float tq = red[1][0][t] + red[1][1][t] + red[1][2][t] + red[1][3][t];
            float* dst = stats + (size_t)(blockIdx.x & 63) * 256;
            atomicAdd(&dst[t], ts);
            atomicAdd(&dst[128 + t], tq);
        }
    }
}

// ---------------- BN finalize: reduce 64 stat buckets -> scale/shift ----------------
__global__ __launch_bounds__(128) void bn_fin_k(const float* __restrict__ stats,
                                                const float* __restrict__ g,
                                                const float* __restrict__ beta,
                                                float* __restrict__ ss) {
    int c = threadIdx.x;
    float sv = 0.f, qv = 0.f;
    #pragma unroll 8
    for (int i = 0; i < 64; ++i) {
        sv += stats[i * 256 + c];
        qv += stats[i * 256 + 128 + c];
    }
    float mean = sv * (1.0f / NN);
    float var = qv * (1.0f / NN) - mean * mean;
    float sc = g[c] * rsqrtf(var + BN_EPS);
    ss[c] = sc;
    ss[128 + c] = beta[c] - mean * sc;
}

// ---------------- global mean pool sum (bf16 input) ----------------
__global__ __launch_bounds__(128) void pool_sum_k(const unsigned int* __restrict__ h16,
                                                  const int* __restrict__ batch,
                                                  float* __restrict__ sums) {
    int r0 = blockIdx.x * POOL_CHUNK;
    int r1 = min(r0 + POOL_CHUNK, NN);
    if (r0 >= NN) return;
    int c = threadIdx.x;
    int cp = c >> 1, hi = c & 1;
    float acc = 0.f;
    int g = batch[r0];
    for (int r = r0; r < r1; ++r) {
        int gr = batch[r];
        if (gr != g) {
            atomicAdd(&sums[g * 128 + c], acc);
            acc = 0.f;
            g = gr;
        }
        unsigned int v = h16[(size_t)r * 64 + cp];
        acc += hi ? bf_hi(v) : bf_lo(v);
    }
    atomicAdd(&sums[g * 128 + c], acc);
}

__device__ __forceinline__ int lower_bound_dev(const int* __restrict__ a, int n, int key) {
    int lo = 0, hi = n;
    while (lo < hi) {
        int mid = (lo + hi) >> 1;
        if (a[mid] < key) lo = mid + 1; else hi = mid;
    }
    return lo;
}

// ---------------- MLP head (pool-div fused) ----------------
__global__ __launch_bounds__(128) void head_k(const float* __restrict__ psum,
                                              const int* __restrict__ batch,
                                              const float* __restrict__ W0, const float* __restrict__ b0,
                                              const float* __restrict__ W1, const float* __restrict__ b1,
                                              const float* __restrict__ W2, const float* __restrict__ b2,
                                              float* __restrict__ out) {
    __shared__ float r0[128], r1[128];
    int g = blockIdx.x, t = threadIdx.x;
    int a = lower_bound_dev(batch, NN, g);
    int b = lower_bound_dev(batch, NN, g + 1);
    float inv = 1.0f / fmaxf((float)(b - a), 1.0f);
    r0[t] = psum[g * 128 + t] * inv;
    __syncthreads();
    float acc = b0[t];
    for (int k = 0; k < 128; ++k) acc += r0[k] * W0[k * 128 + t];
    r1[t] = gelu_f(acc);
    __syncthreads();
    acc = b1[t];
    for (int k = 0; k < 128; ++k) acc += r1[k] * W1[k * 128 + t];
    float y = gelu_f(acc);
    __syncthreads();
    r0[t] = y;
    __syncthreads();
    if (t < 10) {
        acc = b2[t];
        for (int k = 0; k < 128; ++k) acc += r0[k] * W2[k * 10 + t];
        out[g * 10 + t] = acc;
    }
}

extern "C" void kernel_launch(void* const* d_in, const int* in_sizes, int n_in,
                              void* d_out, int out_size, void* d_ws, size_t ws_size,
                              hipStream_t stream) {
    const float* x      = (const float*)d_in[0];
    const int*   ei     = (const int*)d_in[1];
    const int*   batch  = (const int*)d_in[2];
    const float* Wb0    = (const float*)d_in[4];
    const float* bb0    = (const float*)d_in[5];
    const float* gb0    = (const float*)d_in[6];
    const float* betab0 = (const float*)d_in[7];
    const float* Wb1    = (const float*)d_in[8];
    const float* bb1    = (const float*)d_in[9];
    const float* Wa0    = (const float*)d_in[10];
    const float* ba0    = (const float*)d_in[11];
    const float* ga0    = (const float*)d_in[12];
    const float* bea0   = (const float*)d_in[13];
    const float* Wa1    = (const float*)d_in[14];
    const float* ba1    = (const float*)d_in[15];
    const float* ga1    = (const float*)d_in[16];
    const float* bea1   = (const float*)d_in[17];
    const float* Wa2    = (const float*)d_in[18];
    const float* ba2    = (const float*)d_in[19];
    const float* Wh0    = (const float*)d_in[20];
    const float* bh0    = (const float*)d_in[21];
    const float* Wh1    = (const float*)d_in[22];
    const float* bh1    = (const float*)d_in[23];
    const float* Wh2    = (const float*)d_in[24];
    const float* bh2    = (const float*)d_in[25];
    float* out = (float*)d_out;

    char* ws = (char*)d_ws;
    unsigned int* hw16 = (unsigned int*)ws;             ws += (size_t)(NN + 16) * 64 * 4; // GEMM out + sentinel zero row NN
    unsigned int* hB   = (unsigned int*)ws;             ws += (size_t)NN * 64 * 4;   // conv out (bf16x2)
    unsigned int* hC   = (unsigned int*)ws;             ws += (size_t)NN * 64 * 4;
    float* dinv    = (float*)ws;                        ws += (size_t)NN * 4;
    int*   row_ptr = (int*)ws;                          ws += (size_t)(NN + 4) * 4;
    int*   row_cnt = (int*)ws;                          ws += (size_t)NN * 4;
    int*   csr_src = (int*)ws;                          ws += (size_t)NBKT * CAP * 4;  // strided index space
    unsigned int* part = (unsigned int*)ws;             ws += (size_t)NBKT * CAP * 4;  // 4B packed edges
    unsigned short* wf = (unsigned short*)ws;           ws += (size_t)5 * 16384 * 2;
    float* ssbuf   = (float*)ws;                        ws += 256 * 4;
    // ---- zero region (single memset) ----
    char* zbase = ws;
    int*   btail   = (int*)ws;                          ws += 128 * 4;
    float* stats3  = (float*)ws;                        ws += (size_t)3 * 64 * 256 * 4;
    float* psum    = (float*)ws;                        ws += (size_t)NG * CH * 4;
    size_t zbytes = (size_t)(ws - zbase);

    unsigned short* wfb0 = wf;
    unsigned short* wfb1 = wf + 16384;
    unsigned short* wfa0 = wf + 2 * 16384;
    unsigned short* wfa1 = wf + 3 * 16384;
    unsigned short* wfa2 = wf + 4 * 16384;

    float* st0 = stats3;
    float* st1 = stats3 + 64 * 256;
    float* st2 = stats3 + 2 * 64 * 256;

    hipMemsetAsync(zbase, 0, zbytes, stream);
    hipMemsetAsync(hw16 + (size_t)NN * 64, 0, 256, stream);   // sentinel zero row

    // CSR build + W-pack (fused): capacity-strided buckets, 4B packed partition
    part_k<<<NPART + 40, 256, 0, stream>>>(ei, btail, part, Wb0, Wb1, Wa0, Wa1, Wa2, wf);
    cscat2_k<<<NBKT, 256, 0, stream>>>(part, btail, row_ptr, row_cnt, dinv, csr_src);

    auto agg = [&](const float* b, unsigned int* o, float* stats) {
        csr_agg_k<<<(NN / 2 * 64) / 256, 256, 0, stream>>>(row_ptr, row_cnt, csr_src,
                                                           hw16, b, dinv, o, stats);
    };
    auto bn_fin = [&](const float* st, const float* g, const float* beta) {
        bn_fin_k<<<1, 128, 0, stream>>>(st, g, beta, ssbuf);
    };

    // conv b0 (fp32 input x)
    gemm_f32_k<<<(NN + 63) / 64, 256, 0, stream>>>(x, wfb0, dinv, hw16);
    agg(bb0, hB, st0);
    bn_fin(st0, gb0, betab0);
    // conv b1 (BN+GELU fused on load)
    gemm_bf16_k<<<(NN + 63) / 64, 256, 0, stream>>>(hB, wfb1, ssbuf, dinv, hw16);
    agg(bb1, hC, nullptr);
    // conv a0 (no BN on input)
    gemm_bf16_k<<<(NN + 63) / 64, 256, 0, stream>>>(hC, wfa0, nullptr, dinv, hw16);
    agg(ba0, hB, st1);
    bn_fin(st1, ga0, bea0);
    // conv a1
    gemm_bf16_k<<<(NN + 63) / 64, 256, 0, stream>>>(hB, wfa1, ssbuf, dinv, hw16);
    agg(ba1, hC, st2);
    bn_fin(st2, ga1, bea1);
    // conv a2
    gemm_bf16_k<<<(NN + 63) / 64, 256, 0, stream>>>(hC, wfa2, ssbuf, dinv, hw16);
    agg(ba2, hB, nullptr);

    pool_sum_k<<<(NN + POOL_CHUNK - 1) / POOL_CHUNK, 128, 0, stream>>>(hB, batch, psum);
    head_k<<<NG, 128, 0, stream>>>(psum, batch, Wh0, bh0, Wh1, bh1, Wh2, bh2, out);
}